// Round 3
// baseline (1730.259 us; speedup 1.0000x reference)
//
#include <hip/hip_runtime.h>
#include <hip/hip_fp16.h>
#include <hip/hip_cooperative_groups.h>
#include <math.h>

namespace cg = cooperative_groups;

// Problem constants (fixed by the reference)
#define NN 20000
#define EE 5000
#define DD 128
#define ATT 32
#define NUM_LAYERS 4
#define LN_EPS 1e-5f
#define DEG_EPS 1e-12f

// Padded ELL capacities. Edge degree ~ Binomial(20000,0.01): mean 200, max ~260
// -> cap 320. Node degree ~ Binomial(5000,0.01): mean 50, max ~82 -> cap 128.
#define ECAP 320
#define NCAP 128
// Edge cursor/degree array padded to one counter per 128 B cache line.
#define CSTRIDE 32

typedef float vfloat4 __attribute__((ext_vector_type(4)));

__device__ inline unsigned pack2h(float x, float y) {
    return __builtin_bit_cast(unsigned, __floats2half2_rn(x, y));
}
__device__ inline void acc8(float* a, uint4 u) {
    __half2 h;
    h = __builtin_bit_cast(__half2, u.x); a[0] += __low2float(h); a[1] += __high2float(h);
    h = __builtin_bit_cast(__half2, u.y); a[2] += __low2float(h); a[3] += __high2float(h);
    h = __builtin_bit_cast(__half2, u.z); a[4] += __low2float(h); a[5] += __high2float(h);
    h = __builtin_bit_cast(__half2, u.w); a[6] += __low2float(h); a[7] += __high2float(h);
}

// ===========================================================================
// R10: single cooperative mega-kernel. All phases fused, grid-wide barriers
// between them. Purpose: (a) kill launch gaps, (b) make our work the top-1
// rocprof dispatch so we finally get counters (all previous rounds the harness
// poison fills drowned every per-kernel dispatch).
// ===========================================================================

// ---- edge gather phase (block-stride over edges) --------------------------
template <bool FINAL>
__device__ __forceinline__ void edge_phase(
    const __half* __restrict__ xh, const int* __restrict__ cur,
    const int* __restrict__ el, __half* __restrict__ outh,
    float* __restrict__ eout, const float* __restrict__ W,
    const float* __restrict__ bb, const float* __restrict__ qv,
    float* __restrict__ t, int* ilst, float (*part)[16][8], float* rowbuf) {
    const int tid = threadIdx.x;
    const int lane16 = tid & 15;
    const int s = tid >> 4;        // stream 0..15
    const int wave = tid >> 6;
    for (int e = blockIdx.x; e < EE; e += gridDim.x) {
        __syncthreads();           // protect shared reuse across e iterations
        const int cnt = cur[e << 5];
        const int c = min(cnt, ECAP);
        const int* lst = el + (size_t)e * ECAP;
        for (int k = tid; k < c; k += 256) ilst[k] = lst[k];
        __syncthreads();
        float a[8] = {0, 0, 0, 0, 0, 0, 0, 0};
        float b[8] = {0, 0, 0, 0, 0, 0, 0, 0};
        int i = s;
        for (; i + 48 < c; i += 64) {   // 4 rows in flight (R9-proven)
            const int n0 = ilst[i];
            const int n1 = ilst[i + 16];
            const int n2 = ilst[i + 32];
            const int n3 = ilst[i + 48];
            const uint4 u0 = *reinterpret_cast<const uint4*>(xh + n0 * DD + lane16 * 8);
            const uint4 u1 = *reinterpret_cast<const uint4*>(xh + n1 * DD + lane16 * 8);
            const uint4 u2 = *reinterpret_cast<const uint4*>(xh + n2 * DD + lane16 * 8);
            const uint4 u3 = *reinterpret_cast<const uint4*>(xh + n3 * DD + lane16 * 8);
            acc8(a, u0); acc8(b, u1); acc8(a, u2); acc8(b, u3);
        }
        for (; i + 16 < c; i += 32) {
            const int n0 = ilst[i];
            const int n1 = ilst[i + 16];
            const uint4 u0 = *reinterpret_cast<const uint4*>(xh + n0 * DD + lane16 * 8);
            const uint4 u1 = *reinterpret_cast<const uint4*>(xh + n1 * DD + lane16 * 8);
            acc8(a, u0); acc8(b, u1);
        }
        if (i < c) {
            acc8(a, *reinterpret_cast<const uint4*>(xh + ilst[i] * DD + lane16 * 8));
        }
#pragma unroll
        for (int k = 0; k < 8; k++) {
            float v = a[k] + b[k];
            v += __shfl_down(v, 16);
            v += __shfl_down(v, 32);
            a[k] = v;
        }
        if ((tid & 63) < 16) {
#pragma unroll
            for (int k = 0; k < 8; k++) part[wave][lane16][k] = a[k];
        }
        __syncthreads();
        if (tid < 16) {
            const float inv = 1.0f / fmaxf((float)cnt, DEG_EPS);
            float o[8];
#pragma unroll
            for (int k = 0; k < 8; k++)
                o[k] = (part[0][tid][k] + part[1][tid][k] + part[2][tid][k] + part[3][tid][k]) * inv;
            if (!FINAL) {
                uint4 u;
                u.x = pack2h(o[0], o[1]); u.y = pack2h(o[2], o[3]);
                u.z = pack2h(o[4], o[5]); u.w = pack2h(o[6], o[7]);
                *reinterpret_cast<uint4*>(outh + e * DD + tid * 8) = u;
            } else {
#pragma unroll
                for (int k = 0; k < 8; k++) rowbuf[tid * 8 + k] = o[k];
                *reinterpret_cast<float4*>(eout + e * DD + tid * 8) =
                    make_float4(o[0], o[1], o[2], o[3]);
                *reinterpret_cast<float4*>(eout + e * DD + tid * 8 + 4) =
                    make_float4(o[4], o[5], o[6], o[7]);
            }
        }
        if (FINAL) {
            __syncthreads();
            float r = 0.0f;
            if (tid < ATT) {
                float acc = 0.0f;
#pragma unroll 4
                for (int d = 0; d < DD; d++) acc += rowbuf[d] * W[d * ATT + tid];
                r = tanhf(acc + bb[tid]) * qv[tid];
            }
            for (int off = 16; off > 0; off >>= 1) r += __shfl_down(r, off);
            if (tid == 0) t[e] = r;
        }
    }
}

__global__ __launch_bounds__(256, 4) void mega(
    const float* __restrict__ x0, const float* __restrict__ H,
    const float* __restrict__ gamma, const float* __restrict__ beta,
    const float* __restrict__ W, const float* __restrict__ bb,
    const float* __restrict__ qv,
    int* __restrict__ cur, int* __restrict__ nc,
    int* __restrict__ el, int* __restrict__ nl,
    __half* __restrict__ xh0, __half* __restrict__ xA, __half* __restrict__ xB,
    __half* __restrict__ emean, float* __restrict__ eout,
    float* __restrict__ t, float* __restrict__ MS, float* __restrict__ out) {
    cg::grid_group grid = cg::this_grid();
    const int tid = threadIdx.x;

    __shared__ int s_ilst[ECAP];          // edge list / node lists / build lbuf
    __shared__ float s_part[4][16][8];    // partials (edge) / [2][2][16][8] (node)
    __shared__ float s_rowbuf[DD];        // final-edge row / softmax scratch
    __shared__ int s_lcnt;

    // ---------------- Phase 0: adjacency build + x0->fp16 ------------------
    for (int n = blockIdx.x; n < NN; n += gridDim.x) {
        __syncthreads();
        if (tid == 0) s_lcnt = 0;
        __syncthreads();
        const vfloat4* row = reinterpret_cast<const vfloat4*>(H + (size_t)n * EE);
        for (int i = tid; i < EE / 4; i += 256) {
            const vfloat4 h = __builtin_nontemporal_load(row + i);
            float v[4] = {h.x, h.y, h.z, h.w};
            const int ebase = i * 4;
#pragma unroll
            for (int k = 0; k < 4; k++) {
                if (v[k] != 0.0f) {
                    int sl = atomicAdd(&s_lcnt, 1);
                    if (sl < NCAP) s_ilst[sl] = ebase + k;
                }
            }
        }
        __syncthreads();
        const int cnt = s_lcnt;
        const int c = min(cnt, NCAP);
        for (int k = tid; k < c; k += 256) {
            const int e = s_ilst[k];
            nl[(size_t)n * NCAP + k] = e;
            const int slot = atomicAdd(&cur[e << 5], 1);
            if (slot < ECAP) el[(size_t)e * ECAP + slot] = n;
        }
        if (tid < 64) {
            const float2 v = reinterpret_cast<const float2*>(x0 + (size_t)n * DD)[tid];
            reinterpret_cast<unsigned*>(xh0 + (size_t)n * DD)[tid] = pack2h(v.x, v.y);
        }
        if (tid == 0) nc[n] = cnt;
    }
    grid.sync();

    // ---------------- 4 layers: edge mean -> node mean + residual + LN -----
    const __half* xin = xh0;
    for (int l = 0; l < NUM_LAYERS; l++) {
        edge_phase<false>(xin, cur, el, emean, nullptr, nullptr, nullptr, nullptr,
                          nullptr, s_ilst, s_part, s_rowbuf);
        grid.sync();

        // node gather + LN: 2 nodes per 256-thread block
        {
            int (*nilst)[NCAP] = reinterpret_cast<int (*)[NCAP]>(s_ilst);
            float (*npart)[2][16][8] = reinterpret_cast<float (*)[2][16][8]>(s_part);
            __half* xout = (l & 1) ? xB : xA;
            const int half = tid >> 7;
            const int ltid = tid & 127;
            const int lane16 = ltid & 15;
            const int s = ltid >> 4;      // stream 0..7
            const int wv = ltid >> 6;     // 0..1 within half
            for (int nb = blockIdx.x * 2; nb < NN; nb += gridDim.x * 2) {
                const int n = nb + half;  // NN even -> always valid
                __syncthreads();
                const int cnt = nc[n];
                const int c = min(cnt, NCAP);
                const int* lst = nl + (size_t)n * NCAP;
                if (ltid < c) nilst[half][ltid] = lst[ltid];
                __syncthreads();
                float a[8] = {0, 0, 0, 0, 0, 0, 0, 0};
                float b[8] = {0, 0, 0, 0, 0, 0, 0, 0};
                int i = s;
                for (; i + 24 < c; i += 32) {   // 4 rows in flight
                    const int e0 = nilst[half][i];
                    const int e1 = nilst[half][i + 8];
                    const int e2 = nilst[half][i + 16];
                    const int e3 = nilst[half][i + 24];
                    const uint4 u0 = *reinterpret_cast<const uint4*>(emean + e0 * DD + lane16 * 8);
                    const uint4 u1 = *reinterpret_cast<const uint4*>(emean + e1 * DD + lane16 * 8);
                    const uint4 u2 = *reinterpret_cast<const uint4*>(emean + e2 * DD + lane16 * 8);
                    const uint4 u3 = *reinterpret_cast<const uint4*>(emean + e3 * DD + lane16 * 8);
                    acc8(a, u0); acc8(b, u1); acc8(a, u2); acc8(b, u3);
                }
                for (; i + 8 < c; i += 16) {
                    const int e0 = nilst[half][i];
                    const int e1 = nilst[half][i + 8];
                    const uint4 u0 = *reinterpret_cast<const uint4*>(emean + e0 * DD + lane16 * 8);
                    const uint4 u1 = *reinterpret_cast<const uint4*>(emean + e1 * DD + lane16 * 8);
                    acc8(a, u0); acc8(b, u1);
                }
                if (i < c) {
                    acc8(a, *reinterpret_cast<const uint4*>(emean + nilst[half][i] * DD + lane16 * 8));
                }
#pragma unroll
                for (int k = 0; k < 8; k++) {
                    float v = a[k] + b[k];
                    v += __shfl_down(v, 16);
                    v += __shfl_down(v, 32);
                    a[k] = v;
                }
                if ((ltid & 63) < 16) {
#pragma unroll
                    for (int k = 0; k < 8; k++) npart[half][wv][lane16][k] = a[k];
                }
                __syncthreads();
                if (ltid < 16) {
                    const float inv = 1.0f / fmaxf((float)cnt, DEG_EPS);
                    const float4 x0a = *reinterpret_cast<const float4*>(x0 + n * DD + ltid * 8);
                    const float4 x0b = *reinterpret_cast<const float4*>(x0 + n * DD + ltid * 8 + 4);
                    float y[8];
                    y[0] = (npart[half][0][ltid][0] + npart[half][1][ltid][0]) * inv + x0a.x;
                    y[1] = (npart[half][0][ltid][1] + npart[half][1][ltid][1]) * inv + x0a.y;
                    y[2] = (npart[half][0][ltid][2] + npart[half][1][ltid][2]) * inv + x0a.z;
                    y[3] = (npart[half][0][ltid][3] + npart[half][1][ltid][3]) * inv + x0a.w;
                    y[4] = (npart[half][0][ltid][4] + npart[half][1][ltid][4]) * inv + x0b.x;
                    y[5] = (npart[half][0][ltid][5] + npart[half][1][ltid][5]) * inv + x0b.y;
                    y[6] = (npart[half][0][ltid][6] + npart[half][1][ltid][6]) * inv + x0b.z;
                    y[7] = (npart[half][0][ltid][7] + npart[half][1][ltid][7]) * inv + x0b.w;
                    float sm = 0.0f, ss = 0.0f;
#pragma unroll
                    for (int k = 0; k < 8; k++) { sm += y[k]; ss += y[k] * y[k]; }
                    for (int off = 8; off > 0; off >>= 1) {
                        sm += __shfl_down(sm, off);
                        ss += __shfl_down(ss, off);
                    }
                    sm = __shfl(sm, 0);
                    ss = __shfl(ss, 0);
                    const float mu = sm * (1.0f / 128.0f);
                    float var = ss * (1.0f / 128.0f) - mu * mu;
                    var = fmaxf(var, 0.0f);
                    const float rstd = 1.0f / sqrtf(var + LN_EPS);
                    const float4 g0 = *reinterpret_cast<const float4*>(gamma + ltid * 8);
                    const float4 g1 = *reinterpret_cast<const float4*>(gamma + ltid * 8 + 4);
                    const float4 b0 = *reinterpret_cast<const float4*>(beta + ltid * 8);
                    const float4 b1 = *reinterpret_cast<const float4*>(beta + ltid * 8 + 4);
                    float gg[8] = {g0.x, g0.y, g0.z, g0.w, g1.x, g1.y, g1.z, g1.w};
                    float bv[8] = {b0.x, b0.y, b0.z, b0.w, b1.x, b1.y, b1.z, b1.w};
                    float o[8];
#pragma unroll
                    for (int k = 0; k < 8; k++) o[k] = (y[k] - mu) * rstd * gg[k] + bv[k];
                    uint4 u;
                    u.x = pack2h(o[0], o[1]); u.y = pack2h(o[2], o[3]);
                    u.z = pack2h(o[4], o[5]); u.w = pack2h(o[6], o[7]);
                    *reinterpret_cast<uint4*>(xout + n * DD + ltid * 8) = u;
                }
            }
        }
        grid.sync();
        xin = (l & 1) ? xB : xA;
    }

    // ---------------- Final edge pass (fp32 + logits) -----------------------
    edge_phase<true>(xin, cur, el, nullptr, eout, W, bb, qv, t,
                     s_ilst, s_part, s_rowbuf);
    grid.sync();

    // ---------------- Softmax stats (block 0) -------------------------------
    if (blockIdx.x == 0) {
        __syncthreads();
        float m = -1e30f;
        for (int i = tid; i < EE; i += 256) m = fmaxf(m, t[i]);
        for (int off = 32; off > 0; off >>= 1) m = fmaxf(m, __shfl_down(m, off));
        if ((tid & 63) == 0) s_rowbuf[tid >> 6] = m;
        __syncthreads();
        if (tid == 0) {
            s_rowbuf[8] = fmaxf(fmaxf(s_rowbuf[0], s_rowbuf[1]),
                                fmaxf(s_rowbuf[2], s_rowbuf[3]));
        }
        __syncthreads();
        const float M = s_rowbuf[8];
        float sum = 0.0f;
        for (int i = tid; i < EE; i += 256) sum += expf(t[i] - M);
        for (int off = 32; off > 0; off >>= 1) sum += __shfl_down(sum, off);
        if ((tid & 63) == 0) s_rowbuf[16 + (tid >> 6)] = sum;
        __syncthreads();
        if (tid == 0) {
            MS[0] = M;
            MS[1] = s_rowbuf[16] + s_rowbuf[17] + s_rowbuf[18] + s_rowbuf[19];
        }
    }
    grid.sync();

    // ---------------- Weighted sum ------------------------------------------
    {
        const int WS = min((int)gridDim.x, 256);
        if (blockIdx.x < WS && tid < 128) {
            const float M = MS[0];
            const float invS = 1.0f / MS[1];
            float acc = 0.0f;
            for (int e = blockIdx.x; e < EE; e += WS) {
                acc += expf(t[e] - M) * eout[e * DD + tid];
            }
            atomicAdd(&out[tid], acc * invS);
        }
    }
}

// ===========================================================================
// Fallback multi-kernel path (R9-proven, 730 us) in case cooperative launch
// is unavailable under graph capture.
// ===========================================================================
__global__ __launch_bounds__(256) void build_adj(
    const float* __restrict__ H, int* __restrict__ cur, int* __restrict__ nc,
    int* __restrict__ el, int* __restrict__ nl,
    const float* __restrict__ x0, __half* __restrict__ xh0) {
    const int n = blockIdx.x;
    const int tid = threadIdx.x;
    __shared__ int lcnt;
    __shared__ int lbuf[NCAP];
    if (tid == 0) lcnt = 0;
    __syncthreads();
    const vfloat4* row = reinterpret_cast<const vfloat4*>(H + (size_t)n * EE);
    for (int i = tid; i < EE / 4; i += 256) {
        const vfloat4 h = __builtin_nontemporal_load(row + i);
        float v[4] = {h.x, h.y, h.z, h.w};
        const int ebase = i * 4;
#pragma unroll
        for (int k = 0; k < 4; k++) {
            if (v[k] != 0.0f) {
                int s = atomicAdd(&lcnt, 1);
                if (s < NCAP) lbuf[s] = ebase + k;
            }
        }
    }
    __syncthreads();
    const int c = min(lcnt, NCAP);
    for (int k = tid; k < c; k += 256) {
        const int e = lbuf[k];
        nl[(size_t)n * NCAP + k] = e;
        const int slot = atomicAdd(&cur[e << 5], 1);
        if (slot < ECAP) el[(size_t)e * ECAP + slot] = n;
    }
    if (tid < 64) {
        const float2 v = reinterpret_cast<const float2*>(x0 + (size_t)n * DD)[tid];
        reinterpret_cast<unsigned*>(xh0 + (size_t)n * DD)[tid] = pack2h(v.x, v.y);
    }
    if (tid == 0) nc[n] = lcnt;
}

template <bool FINAL>
__global__ __launch_bounds__(256) void edge_gather16(
    const __half* __restrict__ xh, const int* __restrict__ cur,
    const int* __restrict__ el, __half* __restrict__ outh,
    float* __restrict__ eout, const float* __restrict__ W,
    const float* __restrict__ bb, const float* __restrict__ qv,
    float* __restrict__ t) {
    __shared__ int ilst[ECAP];
    __shared__ float part[4][16][8];
    __shared__ float rowbuf[DD];
    const int tid = threadIdx.x;
    // body shared with mega via edge_phase, but grid == EE here
    const int e = blockIdx.x;
    const int cnt = cur[e << 5];
    const int c = min(cnt, ECAP);
    const int* lst = el + (size_t)e * ECAP;
    for (int k = tid; k < c; k += 256) ilst[k] = lst[k];
    __syncthreads();
    const int lane16 = tid & 15;
    const int s = tid >> 4;
    const int wave = tid >> 6;
    float a[8] = {0, 0, 0, 0, 0, 0, 0, 0};
    float b[8] = {0, 0, 0, 0, 0, 0, 0, 0};
    int i = s;
    for (; i + 48 < c; i += 64) {
        const int n0 = ilst[i];
        const int n1 = ilst[i + 16];
        const int n2 = ilst[i + 32];
        const int n3 = ilst[i + 48];
        const uint4 u0 = *reinterpret_cast<const uint4*>(xh + n0 * DD + lane16 * 8);
        const uint4 u1 = *reinterpret_cast<const uint4*>(xh + n1 * DD + lane16 * 8);
        const uint4 u2 = *reinterpret_cast<const uint4*>(xh + n2 * DD + lane16 * 8);
        const uint4 u3 = *reinterpret_cast<const uint4*>(xh + n3 * DD + lane16 * 8);
        acc8(a, u0); acc8(b, u1); acc8(a, u2); acc8(b, u3);
    }
    for (; i + 16 < c; i += 32) {
        const int n0 = ilst[i];
        const int n1 = ilst[i + 16];
        const uint4 u0 = *reinterpret_cast<const uint4*>(xh + n0 * DD + lane16 * 8);
        const uint4 u1 = *reinterpret_cast<const uint4*>(xh + n1 * DD + lane16 * 8);
        acc8(a, u0); acc8(b, u1);
    }
    if (i < c) {
        acc8(a, *reinterpret_cast<const uint4*>(xh + ilst[i] * DD + lane16 * 8));
    }
#pragma unroll
    for (int k = 0; k < 8; k++) {
        float v = a[k] + b[k];
        v += __shfl_down(v, 16);
        v += __shfl_down(v, 32);
        a[k] = v;
    }
    if ((tid & 63) < 16) {
#pragma unroll
        for (int k = 0; k < 8; k++) part[wave][lane16][k] = a[k];
    }
    __syncthreads();
    if (tid < 16) {
        const float inv = 1.0f / fmaxf((float)cnt, DEG_EPS);
        float o[8];
#pragma unroll
        for (int k = 0; k < 8; k++)
            o[k] = (part[0][tid][k] + part[1][tid][k] + part[2][tid][k] + part[3][tid][k]) * inv;
        if (!FINAL) {
            uint4 u;
            u.x = pack2h(o[0], o[1]); u.y = pack2h(o[2], o[3]);
            u.z = pack2h(o[4], o[5]); u.w = pack2h(o[6], o[7]);
            *reinterpret_cast<uint4*>(outh + e * DD + tid * 8) = u;
        } else {
#pragma unroll
            for (int k = 0; k < 8; k++) rowbuf[tid * 8 + k] = o[k];
            *reinterpret_cast<float4*>(eout + e * DD + tid * 8) =
                make_float4(o[0], o[1], o[2], o[3]);
            *reinterpret_cast<float4*>(eout + e * DD + tid * 8 + 4) =
                make_float4(o[4], o[5], o[6], o[7]);
        }
    }
    if (FINAL) {
        __syncthreads();
        float r = 0.0f;
        if (tid < ATT) {
            float acc = 0.0f;
#pragma unroll 4
            for (int d = 0; d < DD; d++) acc += rowbuf[d] * W[d * ATT + tid];
            r = tanhf(acc + bb[tid]) * qv[tid];
        }
        for (int off = 16; off > 0; off >>= 1) r += __shfl_down(r, off);
        if (tid == 0) t[e] = r;
    }
}

__global__ __launch_bounds__(128) void node_gather_ln16(
    const __half* __restrict__ emean, const int* __restrict__ nc,
    const int* __restrict__ nl, const float* __restrict__ x0,
    const float* __restrict__ gamma, const float* __restrict__ beta,
    __half* __restrict__ xout) {
    __shared__ int ilst[NCAP];
    __shared__ float part[2][16][8];
    const int n = blockIdx.x;
    const int tid = threadIdx.x;
    const int cnt = nc[n];
    const int c = min(cnt, NCAP);
    const int* lst = nl + (size_t)n * NCAP;
    if (tid < c) ilst[tid] = lst[tid];
    __syncthreads();
    const int lane16 = tid & 15;
    const int s = tid >> 4;
    const int wave = tid >> 6;
    float a[8] = {0, 0, 0, 0, 0, 0, 0, 0};
    float b[8] = {0, 0, 0, 0, 0, 0, 0, 0};
    int i = s;
    for (; i + 24 < c; i += 32) {
        const int e0 = ilst[i];
        const int e1 = ilst[i + 8];
        const int e2 = ilst[i + 16];
        const int e3 = ilst[i + 24];
        const uint4 u0 = *reinterpret_cast<const uint4*>(emean + e0 * DD + lane16 * 8);
        const uint4 u1 = *reinterpret_cast<const uint4*>(emean + e1 * DD + lane16 * 8);
        const uint4 u2 = *reinterpret_cast<const uint4*>(emean + e2 * DD + lane16 * 8);
        const uint4 u3 = *reinterpret_cast<const uint4*>(emean + e3 * DD + lane16 * 8);
        acc8(a, u0); acc8(b, u1); acc8(a, u2); acc8(b, u3);
    }
    for (; i + 8 < c; i += 16) {
        const int e0 = ilst[i];
        const int e1 = ilst[i + 8];
        const uint4 u0 = *reinterpret_cast<const uint4*>(emean + e0 * DD + lane16 * 8);
        const uint4 u1 = *reinterpret_cast<const uint4*>(emean + e1 * DD + lane16 * 8);
        acc8(a, u0); acc8(b, u1);
    }
    if (i < c) {
        acc8(a, *reinterpret_cast<const uint4*>(emean + ilst[i] * DD + lane16 * 8));
    }
#pragma unroll
    for (int k = 0; k < 8; k++) {
        float v = a[k] + b[k];
        v += __shfl_down(v, 16);
        v += __shfl_down(v, 32);
        a[k] = v;
    }
    if ((tid & 63) < 16) {
#pragma unroll
        for (int k = 0; k < 8; k++) part[wave][lane16][k] = a[k];
    }
    __syncthreads();
    if (tid < 16) {
        const float inv = 1.0f / fmaxf((float)cnt, DEG_EPS);
        const float4 x0a = *reinterpret_cast<const float4*>(x0 + n * DD + tid * 8);
        const float4 x0b = *reinterpret_cast<const float4*>(x0 + n * DD + tid * 8 + 4);
        float y[8];
        y[0] = (part[0][tid][0] + part[1][tid][0]) * inv + x0a.x;
        y[1] = (part[0][tid][1] + part[1][tid][1]) * inv + x0a.y;
        y[2] = (part[0][tid][2] + part[1][tid][2]) * inv + x0a.z;
        y[3] = (part[0][tid][3] + part[1][tid][3]) * inv + x0a.w;
        y[4] = (part[0][tid][4] + part[1][tid][4]) * inv + x0b.x;
        y[5] = (part[0][tid][5] + part[1][tid][5]) * inv + x0b.y;
        y[6] = (part[0][tid][6] + part[1][tid][6]) * inv + x0b.z;
        y[7] = (part[0][tid][7] + part[1][tid][7]) * inv + x0b.w;
        float sm = 0.0f, ss = 0.0f;
#pragma unroll
        for (int k = 0; k < 8; k++) { sm += y[k]; ss += y[k] * y[k]; }
        for (int off = 8; off > 0; off >>= 1) {
            sm += __shfl_down(sm, off);
            ss += __shfl_down(ss, off);
        }
        sm = __shfl(sm, 0);
        ss = __shfl(ss, 0);
        const float mu = sm * (1.0f / 128.0f);
        float var = ss * (1.0f / 128.0f) - mu * mu;
        var = fmaxf(var, 0.0f);
        const float rstd = 1.0f / sqrtf(var + LN_EPS);
        const float4 g0 = *reinterpret_cast<const float4*>(gamma + tid * 8);
        const float4 g1 = *reinterpret_cast<const float4*>(gamma + tid * 8 + 4);
        const float4 b0 = *reinterpret_cast<const float4*>(beta + tid * 8);
        const float4 b1 = *reinterpret_cast<const float4*>(beta + tid * 8 + 4);
        float gg[8] = {g0.x, g0.y, g0.z, g0.w, g1.x, g1.y, g1.z, g1.w};
        float bb[8] = {b0.x, b0.y, b0.z, b0.w, b1.x, b1.y, b1.z, b1.w};
        float o[8];
#pragma unroll
        for (int k = 0; k < 8; k++) o[k] = (y[k] - mu) * rstd * gg[k] + bb[k];
        uint4 u;
        u.x = pack2h(o[0], o[1]); u.y = pack2h(o[2], o[3]);
        u.z = pack2h(o[4], o[5]); u.w = pack2h(o[6], o[7]);
        *reinterpret_cast<uint4*>(xout + n * DD + tid * 8) = u;
    }
}

__global__ __launch_bounds__(1024) void softmax_stats(
    const float* __restrict__ t, float* __restrict__ MS) {
    __shared__ float red[16];
    __shared__ float smax;
    const int tid = threadIdx.x;
    const int wid = tid >> 6;
    float m = -1e30f;
    for (int i = tid; i < EE; i += 1024) m = fmaxf(m, t[i]);
    for (int off = 32; off > 0; off >>= 1) m = fmaxf(m, __shfl_down(m, off));
    if ((tid & 63) == 0) red[wid] = m;
    __syncthreads();
    if (tid < 64) {
        float v = (tid < 16) ? red[tid] : -1e30f;
        for (int off = 8; off > 0; off >>= 1) v = fmaxf(v, __shfl_down(v, off));
        if (tid == 0) smax = v;
    }
    __syncthreads();
    const float M = smax;
    float sum = 0.0f;
    for (int i = tid; i < EE; i += 1024) sum += expf(t[i] - M);
    for (int off = 32; off > 0; off >>= 1) sum += __shfl_down(sum, off);
    if ((tid & 63) == 0) red[wid] = sum;
    __syncthreads();
    if (tid < 64) {
        float v = (tid < 16) ? red[tid] : 0.0f;
        for (int off = 8; off > 0; off >>= 1) v += __shfl_down(v, off);
        if (tid == 0) { MS[0] = M; MS[1] = v; }
    }
}

__global__ __launch_bounds__(128) void weighted_sum(
    const float* __restrict__ eout, const float* __restrict__ t,
    const float* __restrict__ MS, float* __restrict__ out) {
    const int d = threadIdx.x;
    const float M = MS[0];
    const float invS = 1.0f / MS[1];
    float acc = 0.0f;
    for (int e = blockIdx.x; e < EE; e += gridDim.x) {
        const float w = expf(t[e] - M);
        acc += w * eout[e * DD + d];
    }
    atomicAdd(&out[d], acc * invS);
}

extern "C" void kernel_launch(void* const* d_in, const int* in_sizes, int n_in,
                              void* d_out, int out_size, void* d_ws, size_t ws_size,
                              hipStream_t stream) {
    const float* x0 = (const float*)d_in[0];     // [N, D]
    const float* H = (const float*)d_in[1];      // [N, E]
    const float* gamma = (const float*)d_in[2];  // [D]
    const float* beta = (const float*)d_in[3];   // [D]
    const float* W = (const float*)d_in[4];      // [D, ATT]
    const float* b = (const float*)d_in[5];      // [ATT]
    const float* qv = (const float*)d_in[6];     // [ATT]
    float* out = (float*)d_out;                  // [D]

    // Workspace layout (all offsets 16B-aligned). Total ~37 MB.
    char* w = (char*)d_ws;
    int* cur = (int*)w;       w += (size_t)EE * CSTRIDE * 4;
    int* nc = (int*)w;        w += (size_t)NN * 4;
    int* el = (int*)w;        w += (size_t)EE * ECAP * 4;
    int* nl = (int*)w;        w += (size_t)NN * NCAP * 4;
    __half* xh0 = (__half*)w; w += (size_t)NN * DD * 2;
    __half* xA = (__half*)w;  w += (size_t)NN * DD * 2;
    __half* xB = (__half*)w;  w += (size_t)NN * DD * 2;
    __half* emean = (__half*)w; w += (size_t)EE * DD * 2;
    float* eout = (float*)w;  w += (size_t)EE * DD * 4;
    float* t = (float*)w;     w += (size_t)EE * 4;
    float* MS = (float*)w;    w += 16;

    hipMemsetAsync(cur, 0, (size_t)EE * CSTRIDE * 4, stream);
    hipMemsetAsync(d_out, 0, (size_t)DD * sizeof(float), stream);

    // Grid sized for guaranteed co-residency (one-time occupancy query).
    static int grid = 0;
    if (grid == 0) {
        int mb = 0;
        if (hipOccupancyMaxActiveBlocksPerMultiprocessor(&mb, mega, 256, 0)
                != hipSuccess || mb <= 0)
            mb = 4;
        grid = mb * 256;          // 256 CUs on MI355X
        if (grid > 1024) grid = 1024;
        if (grid < 256) grid = 256;
    }

    void* args[] = {(void*)&x0, (void*)&H, (void*)&gamma, (void*)&beta,
                    (void*)&W, (void*)&b, (void*)&qv,
                    (void*)&cur, (void*)&nc, (void*)&el, (void*)&nl,
                    (void*)&xh0, (void*)&xA, (void*)&xB,
                    (void*)&emean, (void*)&eout, (void*)&t, (void*)&MS,
                    (void*)&out};
    hipError_t err = hipLaunchCooperativeKernel(
        mega, dim3(grid), dim3(256), args, 0, stream);

    if (err != hipSuccess) {
        // Fallback: R9-proven multi-kernel path.
        (void)hipGetLastError();
        build_adj<<<NN, 256, 0, stream>>>(H, cur, nc, el, nl, x0, xh0);
        const __half* xin = xh0;
        __half* bufs[2] = {xA, xB};
        for (int l = 0; l < NUM_LAYERS; l++) {
            edge_gather16<false><<<EE, 256, 0, stream>>>(
                xin, cur, el, emean, nullptr, nullptr, nullptr, nullptr, nullptr);
            node_gather_ln16<<<NN, 128, 0, stream>>>(
                emean, nc, nl, x0, gamma, beta, bufs[l & 1]);
            xin = bufs[l & 1];
        }
        edge_gather16<true><<<EE, 256, 0, stream>>>(
            xin, cur, el, nullptr, eout, W, b, qv, t);
        softmax_stats<<<1, 1024, 0, stream>>>(t, MS);
        weighted_sum<<<256, 128, 0, stream>>>(eout, t, MS, out);
    }
}

// Round 4
// 1477.233 us; speedup vs baseline: 1.1713x; 1.1713x over previous
//
#include <hip/hip_runtime.h>
#include <hip/hip_fp16.h>
#include <math.h>

// Problem constants (fixed by the reference)
#define NN 20000
#define EE 5000
#define DD 128
#define ATT 32
#define NUM_LAYERS 4
#define LN_EPS 1e-5f
#define DEG_EPS 1e-12f

// Padded ELL capacities. Edge degree ~ Binomial(20000,0.01): mean 200, max ~260
// -> cap 320. Node degree ~ Binomial(5000,0.01): mean 50, max ~82 -> cap 128.
#define ECAP 320
#define NCAP 128
// Edge cursor/degree array padded to one counter per 128 B cache line.
#define CSTRIDE 32

typedef float vfloat4 __attribute__((ext_vector_type(4)));

__device__ inline unsigned pack2h(float x, float y) {
    return __builtin_bit_cast(unsigned, __floats2half2_rn(x, y));
}
__device__ inline void acc8(float* a, uint4 u) {
    __half2 h;
    h = __builtin_bit_cast(__half2, u.x); a[0] += __low2float(h); a[1] += __high2float(h);
    h = __builtin_bit_cast(__half2, u.y); a[2] += __low2float(h); a[3] += __high2float(h);
    h = __builtin_bit_cast(__half2, u.z); a[4] += __low2float(h); a[5] += __high2float(h);
    h = __builtin_bit_cast(__half2, u.w); a[6] += __low2float(h); a[7] += __high2float(h);
}

// ---------------------------------------------------------------------------
// R11: MEASUREMENT ROUND. Structure identical to the R9 multi-kernel path
// (730 us proven). Each suspect kernel gets an idempotent `reps` repeat so
// one amplified dispatch per phase exceeds the harness poison fills (~247 us)
// and surfaces in the rocprof top-5 with its own counters. Repeats recompute
// identical values -> correctness unchanged.
// ---------------------------------------------------------------------------

// Adjacency build. reps re-runs ONLY the H-scan phase (HBM stream + LDS
// atomics); the global scatter / nc / fp16-convert run on the LAST rep only,
// so cursor atomics still fire exactly once.
__global__ __launch_bounds__(256) void build_adj(
    const float* __restrict__ H, int* __restrict__ cur, int* __restrict__ nc,
    int* __restrict__ el, int* __restrict__ nl,
    const float* __restrict__ x0, __half* __restrict__ xh0, int reps) {
    const int n = blockIdx.x;
    const int tid = threadIdx.x;
    __shared__ int lcnt;
    __shared__ int lbuf[NCAP];
    const vfloat4* row = reinterpret_cast<const vfloat4*>(H + (size_t)n * EE);
    for (int rep = 0; rep < reps; rep++) {
        __syncthreads();
        if (tid == 0) lcnt = 0;
        __syncthreads();
        for (int i = tid; i < EE / 4; i += 256) {
            const vfloat4 h = __builtin_nontemporal_load(row + i);
            float v[4] = {h.x, h.y, h.z, h.w};
            const int ebase = i * 4;
#pragma unroll
            for (int k = 0; k < 4; k++) {
                if (v[k] != 0.0f) {
                    int s = atomicAdd(&lcnt, 1);
                    if (s < NCAP) lbuf[s] = ebase + k;
                }
            }
        }
        __syncthreads();
        if (rep == reps - 1) {
            const int c = min(lcnt, NCAP);
            for (int k = tid; k < c; k += 256) {
                const int e = lbuf[k];
                nl[(size_t)n * NCAP + k] = e;
                const int slot = atomicAdd(&cur[e << 5], 1);
                if (slot < ECAP) el[(size_t)e * ECAP + slot] = n;
            }
            if (tid < 64) {
                const float2 v = reinterpret_cast<const float2*>(x0 + (size_t)n * DD)[tid];
                reinterpret_cast<unsigned*>(xh0 + (size_t)n * DD)[tid] = pack2h(v.x, v.y);
            }
            if (tid == 0) nc[n] = lcnt;
        }
    }
}

// Edge gather (R9 config: 16-lane groups, 4 rows in flight). reps wraps the
// accumulate+reduce+write body; all writes are idempotent.
template <bool FINAL>
__global__ __launch_bounds__(256) void edge_gather16(
    const __half* __restrict__ xh, const int* __restrict__ cur,
    const int* __restrict__ el, __half* __restrict__ outh,
    float* __restrict__ eout, const float* __restrict__ W,
    const float* __restrict__ bb, const float* __restrict__ qv,
    float* __restrict__ t, int reps) {
    __shared__ int ilst[ECAP];
    __shared__ float part[4][16][8];
    __shared__ float rowbuf[DD];
    const int e = blockIdx.x;
    const int tid = threadIdx.x;
    const int cnt = cur[e << 5];
    const int c = min(cnt, ECAP);
    const int* lst = el + (size_t)e * ECAP;
    for (int k = tid; k < c; k += 256) ilst[k] = lst[k];
    __syncthreads();
    const int lane16 = tid & 15;
    const int s = tid >> 4;        // stream 0..15
    const int wave = tid >> 6;
    for (int rep = 0; rep < reps; rep++) {
        float a[8] = {0, 0, 0, 0, 0, 0, 0, 0};
        float b[8] = {0, 0, 0, 0, 0, 0, 0, 0};
        int i = s;
        for (; i + 48 < c; i += 64) {   // 4 rows in flight
            const int n0 = ilst[i];
            const int n1 = ilst[i + 16];
            const int n2 = ilst[i + 32];
            const int n3 = ilst[i + 48];
            const uint4 u0 = *reinterpret_cast<const uint4*>(xh + n0 * DD + lane16 * 8);
            const uint4 u1 = *reinterpret_cast<const uint4*>(xh + n1 * DD + lane16 * 8);
            const uint4 u2 = *reinterpret_cast<const uint4*>(xh + n2 * DD + lane16 * 8);
            const uint4 u3 = *reinterpret_cast<const uint4*>(xh + n3 * DD + lane16 * 8);
            acc8(a, u0); acc8(b, u1); acc8(a, u2); acc8(b, u3);
        }
        for (; i + 16 < c; i += 32) {
            const int n0 = ilst[i];
            const int n1 = ilst[i + 16];
            const uint4 u0 = *reinterpret_cast<const uint4*>(xh + n0 * DD + lane16 * 8);
            const uint4 u1 = *reinterpret_cast<const uint4*>(xh + n1 * DD + lane16 * 8);
            acc8(a, u0); acc8(b, u1);
        }
        if (i < c) {
            acc8(a, *reinterpret_cast<const uint4*>(xh + ilst[i] * DD + lane16 * 8));
        }
#pragma unroll
        for (int k = 0; k < 8; k++) {
            float v = a[k] + b[k];
            v += __shfl_down(v, 16);
            v += __shfl_down(v, 32);
            a[k] = v;
        }
        if ((tid & 63) < 16) {
#pragma unroll
            for (int k = 0; k < 8; k++) part[wave][lane16][k] = a[k];
        }
        __syncthreads();
        if (tid < 16) {
            const float inv = 1.0f / fmaxf((float)cnt, DEG_EPS);
            float o[8];
#pragma unroll
            for (int k = 0; k < 8; k++)
                o[k] = (part[0][tid][k] + part[1][tid][k] + part[2][tid][k] + part[3][tid][k]) * inv;
            if (!FINAL) {
                uint4 u;
                u.x = pack2h(o[0], o[1]); u.y = pack2h(o[2], o[3]);
                u.z = pack2h(o[4], o[5]); u.w = pack2h(o[6], o[7]);
                *reinterpret_cast<uint4*>(outh + e * DD + tid * 8) = u;
            } else {
#pragma unroll
                for (int k = 0; k < 8; k++) rowbuf[tid * 8 + k] = o[k];
                *reinterpret_cast<float4*>(eout + e * DD + tid * 8) =
                    make_float4(o[0], o[1], o[2], o[3]);
                *reinterpret_cast<float4*>(eout + e * DD + tid * 8 + 4) =
                    make_float4(o[4], o[5], o[6], o[7]);
            }
        }
        if (FINAL) {
            __syncthreads();
            float r = 0.0f;
            if (tid < ATT) {
                float acc = 0.0f;
#pragma unroll 4
                for (int d = 0; d < DD; d++) acc += rowbuf[d] * W[d * ATT + tid];
                r = tanhf(acc + bb[tid]) * qv[tid];
            }
            for (int off = 16; off > 0; off >>= 1) r += __shfl_down(r, off);
            if (tid == 0) t[e] = r;
        }
        __syncthreads();   // protect part[]/rowbuf reuse across reps
    }
}

// Node gather + residual + LayerNorm (R9 config). reps wraps the body.
__global__ __launch_bounds__(128) void node_gather_ln16(
    const __half* __restrict__ emean, const int* __restrict__ nc,
    const int* __restrict__ nl, const float* __restrict__ x0,
    const float* __restrict__ gamma, const float* __restrict__ beta,
    __half* __restrict__ xout, int reps) {
    __shared__ int ilst[NCAP];
    __shared__ float part[2][16][8];
    const int n = blockIdx.x;
    const int tid = threadIdx.x;
    const int cnt = nc[n];
    const int c = min(cnt, NCAP);
    const int* lst = nl + (size_t)n * NCAP;
    if (tid < c) ilst[tid] = lst[tid];
    __syncthreads();
    const int lane16 = tid & 15;
    const int s = tid >> 4;        // stream 0..7
    const int wave = tid >> 6;
    for (int rep = 0; rep < reps; rep++) {
        float a[8] = {0, 0, 0, 0, 0, 0, 0, 0};
        float b[8] = {0, 0, 0, 0, 0, 0, 0, 0};
        int i = s;
        for (; i + 24 < c; i += 32) {   // 4 rows in flight
            const int e0 = ilst[i];
            const int e1 = ilst[i + 8];
            const int e2 = ilst[i + 16];
            const int e3 = ilst[i + 24];
            const uint4 u0 = *reinterpret_cast<const uint4*>(emean + e0 * DD + lane16 * 8);
            const uint4 u1 = *reinterpret_cast<const uint4*>(emean + e1 * DD + lane16 * 8);
            const uint4 u2 = *reinterpret_cast<const uint4*>(emean + e2 * DD + lane16 * 8);
            const uint4 u3 = *reinterpret_cast<const uint4*>(emean + e3 * DD + lane16 * 8);
            acc8(a, u0); acc8(b, u1); acc8(a, u2); acc8(b, u3);
        }
        for (; i + 8 < c; i += 16) {
            const int e0 = ilst[i];
            const int e1 = ilst[i + 8];
            const uint4 u0 = *reinterpret_cast<const uint4*>(emean + e0 * DD + lane16 * 8);
            const uint4 u1 = *reinterpret_cast<const uint4*>(emean + e1 * DD + lane16 * 8);
            acc8(a, u0); acc8(b, u1);
        }
        if (i < c) {
            acc8(a, *reinterpret_cast<const uint4*>(emean + ilst[i] * DD + lane16 * 8));
        }
#pragma unroll
        for (int k = 0; k < 8; k++) {
            float v = a[k] + b[k];
            v += __shfl_down(v, 16);
            v += __shfl_down(v, 32);
            a[k] = v;
        }
        if ((tid & 63) < 16) {
#pragma unroll
            for (int k = 0; k < 8; k++) part[wave][lane16][k] = a[k];
        }
        __syncthreads();
        if (tid < 16) {
            const float inv = 1.0f / fmaxf((float)cnt, DEG_EPS);
            const float4 x0a = *reinterpret_cast<const float4*>(x0 + n * DD + tid * 8);
            const float4 x0b = *reinterpret_cast<const float4*>(x0 + n * DD + tid * 8 + 4);
            float y[8];
            y[0] = (part[0][tid][0] + part[1][tid][0]) * inv + x0a.x;
            y[1] = (part[0][tid][1] + part[1][tid][1]) * inv + x0a.y;
            y[2] = (part[0][tid][2] + part[1][tid][2]) * inv + x0a.z;
            y[3] = (part[0][tid][3] + part[1][tid][3]) * inv + x0a.w;
            y[4] = (part[0][tid][4] + part[1][tid][4]) * inv + x0b.x;
            y[5] = (part[0][tid][5] + part[1][tid][5]) * inv + x0b.y;
            y[6] = (part[0][tid][6] + part[1][tid][6]) * inv + x0b.z;
            y[7] = (part[0][tid][7] + part[1][tid][7]) * inv + x0b.w;
            float sm = 0.0f, ss = 0.0f;
#pragma unroll
            for (int k = 0; k < 8; k++) { sm += y[k]; ss += y[k] * y[k]; }
            for (int off = 8; off > 0; off >>= 1) {
                sm += __shfl_down(sm, off);
                ss += __shfl_down(ss, off);
            }
            sm = __shfl(sm, 0);
            ss = __shfl(ss, 0);
            const float mu = sm * (1.0f / 128.0f);
            float var = ss * (1.0f / 128.0f) - mu * mu;
            var = fmaxf(var, 0.0f);
            const float rstd = 1.0f / sqrtf(var + LN_EPS);
            const float4 g0 = *reinterpret_cast<const float4*>(gamma + tid * 8);
            const float4 g1 = *reinterpret_cast<const float4*>(gamma + tid * 8 + 4);
            const float4 b0 = *reinterpret_cast<const float4*>(beta + tid * 8);
            const float4 b1 = *reinterpret_cast<const float4*>(beta + tid * 8 + 4);
            float gg[8] = {g0.x, g0.y, g0.z, g0.w, g1.x, g1.y, g1.z, g1.w};
            float bb[8] = {b0.x, b0.y, b0.z, b0.w, b1.x, b1.y, b1.z, b1.w};
            float o[8];
#pragma unroll
            for (int k = 0; k < 8; k++) o[k] = (y[k] - mu) * rstd * gg[k] + bb[k];
            uint4 u;
            u.x = pack2h(o[0], o[1]); u.y = pack2h(o[2], o[3]);
            u.z = pack2h(o[4], o[5]); u.w = pack2h(o[6], o[7]);
            *reinterpret_cast<uint4*>(xout + n * DD + tid * 8) = u;
        }
        __syncthreads();   // protect part[] reuse across reps
    }
}

__global__ __launch_bounds__(1024) void softmax_stats(
    const float* __restrict__ t, float* __restrict__ MS) {
    __shared__ float red[16];
    __shared__ float smax;
    const int tid = threadIdx.x;
    const int wid = tid >> 6;
    float m = -1e30f;
    for (int i = tid; i < EE; i += 1024) m = fmaxf(m, t[i]);
    for (int off = 32; off > 0; off >>= 1) m = fmaxf(m, __shfl_down(m, off));
    if ((tid & 63) == 0) red[wid] = m;
    __syncthreads();
    if (tid < 64) {
        float v = (tid < 16) ? red[tid] : -1e30f;
        for (int off = 8; off > 0; off >>= 1) v = fmaxf(v, __shfl_down(v, off));
        if (tid == 0) smax = v;
    }
    __syncthreads();
    const float M = smax;
    float sum = 0.0f;
    for (int i = tid; i < EE; i += 1024) sum += expf(t[i] - M);
    for (int off = 32; off > 0; off >>= 1) sum += __shfl_down(sum, off);
    if ((tid & 63) == 0) red[wid] = sum;
    __syncthreads();
    if (tid < 64) {
        float v = (tid < 16) ? red[tid] : 0.0f;
        for (int off = 8; off > 0; off >>= 1) v += __shfl_down(v, off);
        if (tid == 0) { MS[0] = M; MS[1] = v; }
    }
}

__global__ __launch_bounds__(128) void weighted_sum(
    const float* __restrict__ eout, const float* __restrict__ t,
    const float* __restrict__ MS, float* __restrict__ out) {
    const int d = threadIdx.x;
    const float M = MS[0];
    const float invS = 1.0f / MS[1];
    float acc = 0.0f;
    for (int e = blockIdx.x; e < EE; e += gridDim.x) {
        const float w = expf(t[e] - M);
        acc += w * eout[e * DD + d];
    }
    atomicAdd(&out[d], acc * invS);
}

extern "C" void kernel_launch(void* const* d_in, const int* in_sizes, int n_in,
                              void* d_out, int out_size, void* d_ws, size_t ws_size,
                              hipStream_t stream) {
    const float* x0 = (const float*)d_in[0];     // [N, D]
    const float* H = (const float*)d_in[1];      // [N, E]
    const float* gamma = (const float*)d_in[2];  // [D]
    const float* beta = (const float*)d_in[3];   // [D]
    const float* W = (const float*)d_in[4];      // [D, ATT]
    const float* b = (const float*)d_in[5];      // [ATT]
    const float* qv = (const float*)d_in[6];     // [ATT]
    float* out = (float*)d_out;                  // [D]

    // Workspace layout (all offsets 16B-aligned). Total ~37 MB.
    char* w = (char*)d_ws;
    int* cur = (int*)w;       w += (size_t)EE * CSTRIDE * 4;
    int* nc = (int*)w;        w += (size_t)NN * 4;
    int* el = (int*)w;        w += (size_t)EE * ECAP * 4;
    int* nl = (int*)w;        w += (size_t)NN * NCAP * 4;
    __half* xh0 = (__half*)w; w += (size_t)NN * DD * 2;
    __half* xA = (__half*)w;  w += (size_t)NN * DD * 2;
    __half* xB = (__half*)w;  w += (size_t)NN * DD * 2;
    __half* emean = (__half*)w; w += (size_t)EE * DD * 2;
    float* eout = (float*)w;  w += (size_t)EE * DD * 4;
    float* t = (float*)w;     w += (size_t)EE * 4;
    float* MS = (float*)w;    w += 16;

    hipMemsetAsync(cur, 0, (size_t)EE * CSTRIDE * 4, stream);
    hipMemsetAsync(d_out, 0, (size_t)DD * sizeof(float), stream);

    // MEASUREMENT ROUND amplification factors (idempotent repeats):
    // build x4, layer-0 edge x8, layer-0 node x16, final edge x8. Each
    // amplified dispatch should exceed the ~247 us poison fills and surface
    // in rocprof top-5 with per-kernel counters.
    build_adj<<<NN, 256, 0, stream>>>(H, cur, nc, el, nl, x0, xh0, 4);

    const __half* xin = xh0;
    __half* bufs[2] = {xA, xB};
    for (int l = 0; l < NUM_LAYERS; l++) {
        edge_gather16<false><<<EE, 256, 0, stream>>>(
            xin, cur, el, emean, nullptr, nullptr, nullptr, nullptr, nullptr,
            (l == 0) ? 8 : 1);
        node_gather_ln16<<<NN, 128, 0, stream>>>(
            emean, nc, nl, x0, gamma, beta, bufs[l & 1], (l == 0) ? 16 : 1);
        xin = bufs[l & 1];
    }

    edge_gather16<true><<<EE, 256, 0, stream>>>(
        xin, cur, el, nullptr, eout, W, b, qv, t, 8);
    softmax_stats<<<1, 1024, 0, stream>>>(t, MS);
    weighted_sum<<<256, 128, 0, stream>>>(eout, t, MS, out);
}

// Round 5
// 742.055 us; speedup vs baseline: 2.3317x; 1.9907x over previous
//
#include <hip/hip_runtime.h>
#include <hip/hip_fp16.h>
#include <math.h>

// Problem constants (fixed by the reference)
#define NN 20000
#define EE 5000
#define DD 128
#define ATT 32
#define NUM_LAYERS 4
#define LN_EPS 1e-5f
#define DEG_EPS 1e-12f

// Padded ELL capacities. Edge degree ~ Binomial(20000,0.01): mean 200, max ~260
// -> cap 320. Node degree ~ Binomial(5000,0.01): mean 50, max ~82 -> cap 128.
#define ECAP 320
#define NCAP 128
// Edge cursor/degree array padded to one counter per 128 B cache line.
#define CSTRIDE 32

typedef float vfloat4 __attribute__((ext_vector_type(4)));

__device__ inline unsigned pack2h(float x, float y) {
    return __builtin_bit_cast(unsigned, __floats2half2_rn(x, y));
}
__device__ inline void acc8(float* a, uint4 u) {
    __half2 h;
    h = __builtin_bit_cast(__half2, u.x); a[0] += __low2float(h); a[1] += __high2float(h);
    h = __builtin_bit_cast(__half2, u.y); a[2] += __low2float(h); a[3] += __high2float(h);
    h = __builtin_bit_cast(__half2, u.z); a[4] += __low2float(h); a[5] += __high2float(h);
    h = __builtin_bit_cast(__half2, u.w); a[6] += __low2float(h); a[7] += __high2float(h);
}

// ---------------------------------------------------------------------------
// R12: node-feature table split into two half-D tables (xlo/xhi, 2.56 MB each,
// each < 4 MB per-XCD L2). Layer edge passes are XCD-partitioned: blocks on
// XCDs 0-3 (blockIdx%8 in 0..3) gather d<64 from xlo, XCDs 4-7 gather d>=64
// from xhi -> each XCD's gather working set is L2-resident. [R11 measured:
// identical gather from a L2-resident 1.28MB table = ~5us vs 37us from the
// 5.12MB LLC-spilling table.] Heuristic only: if blockIdx%8 != XCD, every XCD
// touches both halves = status quo (correctness unaffected).
// ---------------------------------------------------------------------------

// Adjacency build, ONE nontemporal pass over H (R5/R8-proven), x0->fp16
// conversion into split tables fused in the tail (R9-proven).
__global__ __launch_bounds__(256) void build_adj(
    const float* __restrict__ H, int* __restrict__ cur, int* __restrict__ nc,
    int* __restrict__ el, int* __restrict__ nl,
    const float* __restrict__ x0, __half* __restrict__ xlo0,
    __half* __restrict__ xhi0) {
    const int n = blockIdx.x;
    const int tid = threadIdx.x;
    __shared__ int lcnt;
    __shared__ int lbuf[NCAP];
    if (tid == 0) lcnt = 0;
    __syncthreads();
    const vfloat4* row = reinterpret_cast<const vfloat4*>(H + (size_t)n * EE);
    for (int i = tid; i < EE / 4; i += 256) {
        const vfloat4 h = __builtin_nontemporal_load(row + i);
        float v[4] = {h.x, h.y, h.z, h.w};
        const int ebase = i * 4;
#pragma unroll
        for (int k = 0; k < 4; k++) {
            if (v[k] != 0.0f) {
                int s = atomicAdd(&lcnt, 1);
                if (s < NCAP) lbuf[s] = ebase + k;
            }
        }
    }
    __syncthreads();
    const int c = min(lcnt, NCAP);
    for (int k = tid; k < c; k += 256) {
        const int e = lbuf[k];
        nl[(size_t)n * NCAP + k] = e;
        const int slot = atomicAdd(&cur[e << 5], 1);
        if (slot < ECAP) el[(size_t)e * ECAP + slot] = n;
    }
    if (tid < 64) {
        const float2 v = reinterpret_cast<const float2*>(x0 + (size_t)n * DD)[tid];
        const unsigned u = pack2h(v.x, v.y);
        if (tid < 32)
            reinterpret_cast<unsigned*>(xlo0 + (size_t)n * 64)[tid] = u;
        else
            reinterpret_cast<unsigned*>(xhi0 + (size_t)n * 64)[tid - 32] = u;
    }
    if (tid == 0) nc[n] = lcnt;
}

// ---------------------------------------------------------------------------
// Half-D edge gather. Grid = 2*EE = 10000 blocks. blockIdx%8 selects XCD
// group: groups 0-3 -> lo half, 4-7 -> hi half; e = (b>>3)*4 + (b&3).
// 32 streams x 8 lanes, row = 64 fp16 = 128 B = 8 lanes x 16 B; 4 rows in
// flight per stream. Writes its 64-d half into the unified emean row.
// ---------------------------------------------------------------------------
__global__ __launch_bounds__(256) void edge_gather_half(
    const __half* __restrict__ xlo, const __half* __restrict__ xhi,
    const int* __restrict__ cur, const int* __restrict__ el,
    __half* __restrict__ emean) {
    __shared__ int ilst[ECAP];
    __shared__ float part[4][8][8];
    const int b = blockIdx.x;
    const int g = b & 7;
    const int half = g >> 2;
    const int e = (b >> 3) * 4 + (g & 3);
    const int tid = threadIdx.x;
    const int cnt = cur[e << 5];
    const int c = min(cnt, ECAP);
    const int* lst = el + (size_t)e * ECAP;
    for (int k = tid; k < c; k += 256) ilst[k] = lst[k];
    __syncthreads();
    const __half* xt = half ? xhi : xlo;
    const int lane8 = tid & 7;
    const int s = tid >> 3;        // stream 0..31
    const int wave = tid >> 6;
    float a[8] = {0, 0, 0, 0, 0, 0, 0, 0};
    float bacc[8] = {0, 0, 0, 0, 0, 0, 0, 0};
    int i = s;
    for (; i + 96 < c; i += 128) {   // 4 rows in flight
        const int n0 = ilst[i];
        const int n1 = ilst[i + 32];
        const int n2 = ilst[i + 64];
        const int n3 = ilst[i + 96];
        const uint4 u0 = *reinterpret_cast<const uint4*>(xt + n0 * 64 + lane8 * 8);
        const uint4 u1 = *reinterpret_cast<const uint4*>(xt + n1 * 64 + lane8 * 8);
        const uint4 u2 = *reinterpret_cast<const uint4*>(xt + n2 * 64 + lane8 * 8);
        const uint4 u3 = *reinterpret_cast<const uint4*>(xt + n3 * 64 + lane8 * 8);
        acc8(a, u0); acc8(bacc, u1); acc8(a, u2); acc8(bacc, u3);
    }
    for (; i + 32 < c; i += 64) {    // 2-deep tail
        const int n0 = ilst[i];
        const int n1 = ilst[i + 32];
        const uint4 u0 = *reinterpret_cast<const uint4*>(xt + n0 * 64 + lane8 * 8);
        const uint4 u1 = *reinterpret_cast<const uint4*>(xt + n1 * 64 + lane8 * 8);
        acc8(a, u0); acc8(bacc, u1);
    }
    if (i < c) {
        acc8(a, *reinterpret_cast<const uint4*>(xt + ilst[i] * 64 + lane8 * 8));
    }
#pragma unroll
    for (int k = 0; k < 8; k++) {
        float v = a[k] + bacc[k];
        v += __shfl_down(v, 8);
        v += __shfl_down(v, 16);
        v += __shfl_down(v, 32);
        a[k] = v;
    }
    if ((tid & 63) < 8) {
#pragma unroll
        for (int k = 0; k < 8; k++) part[wave][lane8][k] = a[k];
    }
    __syncthreads();
    if (tid < 8) {
        const float inv = 1.0f / fmaxf((float)cnt, DEG_EPS);
        float o[8];
#pragma unroll
        for (int k = 0; k < 8; k++)
            o[k] = (part[0][tid][k] + part[1][tid][k] + part[2][tid][k] + part[3][tid][k]) * inv;
        uint4 u;
        u.x = pack2h(o[0], o[1]); u.y = pack2h(o[2], o[3]);
        u.z = pack2h(o[4], o[5]); u.w = pack2h(o[6], o[7]);
        *reinterpret_cast<uint4*>(emean + (size_t)e * DD + half * 64 + tid * 8) = u;
    }
}

// ---------------------------------------------------------------------------
// Final full-row edge gather + fp32 out + attention logit. Reads the SPLIT
// tables via a per-lane dual base: lane16<8 -> xlo, else xhi. d-mapping is
// identical to the unified layout, so reduction/epilogue are unchanged (R9).
// ---------------------------------------------------------------------------
__global__ __launch_bounds__(256) void edge_final(
    const __half* __restrict__ xlo, const __half* __restrict__ xhi,
    const int* __restrict__ cur, const int* __restrict__ el,
    float* __restrict__ eout, const float* __restrict__ W,
    const float* __restrict__ bb, const float* __restrict__ qv,
    float* __restrict__ t) {
    __shared__ int ilst[ECAP];
    __shared__ float part[4][16][8];
    __shared__ float rowbuf[DD];
    const int e = blockIdx.x;
    const int tid = threadIdx.x;
    const int cnt = cur[e << 5];
    const int c = min(cnt, ECAP);
    const int* lst = el + (size_t)e * ECAP;
    for (int k = tid; k < c; k += 256) ilst[k] = lst[k];
    __syncthreads();
    const int lane16 = tid & 15;
    const int s = tid >> 4;        // stream 0..15
    const int wave = tid >> 6;
    // per-lane base: lanes 0-7 read the lo table, lanes 8-15 the hi table;
    // element offset within the 64-wide row is (lane16&7)*8.
    const __half* base = ((lane16 < 8) ? xlo : xhi) + (lane16 & 7) * 8;
    float a[8] = {0, 0, 0, 0, 0, 0, 0, 0};
    float b[8] = {0, 0, 0, 0, 0, 0, 0, 0};
    int i = s;
    for (; i + 48 < c; i += 64) {   // 4 rows in flight
        const int n0 = ilst[i];
        const int n1 = ilst[i + 16];
        const int n2 = ilst[i + 32];
        const int n3 = ilst[i + 48];
        const uint4 u0 = *reinterpret_cast<const uint4*>(base + n0 * 64);
        const uint4 u1 = *reinterpret_cast<const uint4*>(base + n1 * 64);
        const uint4 u2 = *reinterpret_cast<const uint4*>(base + n2 * 64);
        const uint4 u3 = *reinterpret_cast<const uint4*>(base + n3 * 64);
        acc8(a, u0); acc8(b, u1); acc8(a, u2); acc8(b, u3);
    }
    for (; i + 16 < c; i += 32) {
        const int n0 = ilst[i];
        const int n1 = ilst[i + 16];
        const uint4 u0 = *reinterpret_cast<const uint4*>(base + n0 * 64);
        const uint4 u1 = *reinterpret_cast<const uint4*>(base + n1 * 64);
        acc8(a, u0); acc8(b, u1);
    }
    if (i < c) {
        acc8(a, *reinterpret_cast<const uint4*>(base + ilst[i] * 64));
    }
#pragma unroll
    for (int k = 0; k < 8; k++) {
        float v = a[k] + b[k];
        v += __shfl_down(v, 16);
        v += __shfl_down(v, 32);
        a[k] = v;
    }
    if ((tid & 63) < 16) {
#pragma unroll
        for (int k = 0; k < 8; k++) part[wave][lane16][k] = a[k];
    }
    __syncthreads();
    if (tid < 16) {
        const float inv = 1.0f / fmaxf((float)cnt, DEG_EPS);
        float o[8];
#pragma unroll
        for (int k = 0; k < 8; k++)
            o[k] = (part[0][tid][k] + part[1][tid][k] + part[2][tid][k] + part[3][tid][k]) * inv;
#pragma unroll
        for (int k = 0; k < 8; k++) rowbuf[tid * 8 + k] = o[k];
        *reinterpret_cast<float4*>(eout + e * DD + tid * 8) =
            make_float4(o[0], o[1], o[2], o[3]);
        *reinterpret_cast<float4*>(eout + e * DD + tid * 8 + 4) =
            make_float4(o[4], o[5], o[6], o[7]);
    }
    __syncthreads();
    float r = 0.0f;
    if (tid < ATT) {
        float acc = 0.0f;
#pragma unroll 4
        for (int d = 0; d < DD; d++) acc += rowbuf[d] * W[d * ATT + tid];
        r = tanhf(acc + bb[tid]) * qv[tid];
    }
    for (int off = 16; off > 0; off >>= 1) r += __shfl_down(r, off);
    if (tid == 0) t[e] = r;
}

// ---------------------------------------------------------------------------
// Node gather + residual + LayerNorm (R9 config, emean unified [E][128] which
// is 1.28 MB -> L2-resident, measured ~5us/pass). Output written to the SPLIT
// tables.
// ---------------------------------------------------------------------------
__global__ __launch_bounds__(128) void node_gather_ln16(
    const __half* __restrict__ emean, const int* __restrict__ nc,
    const int* __restrict__ nl, const float* __restrict__ x0,
    const float* __restrict__ gamma, const float* __restrict__ beta,
    __half* __restrict__ xlo, __half* __restrict__ xhi) {
    __shared__ int ilst[NCAP];
    __shared__ float part[2][16][8];
    const int n = blockIdx.x;
    const int tid = threadIdx.x;
    const int cnt = nc[n];
    const int c = min(cnt, NCAP);
    const int* lst = nl + (size_t)n * NCAP;
    if (tid < c) ilst[tid] = lst[tid];
    __syncthreads();
    const int lane16 = tid & 15;
    const int s = tid >> 4;        // stream 0..7
    const int wave = tid >> 6;
    float a[8] = {0, 0, 0, 0, 0, 0, 0, 0};
    float b[8] = {0, 0, 0, 0, 0, 0, 0, 0};
    int i = s;
    for (; i + 24 < c; i += 32) {   // 4 rows in flight
        const int e0 = ilst[i];
        const int e1 = ilst[i + 8];
        const int e2 = ilst[i + 16];
        const int e3 = ilst[i + 24];
        const uint4 u0 = *reinterpret_cast<const uint4*>(emean + e0 * DD + lane16 * 8);
        const uint4 u1 = *reinterpret_cast<const uint4*>(emean + e1 * DD + lane16 * 8);
        const uint4 u2 = *reinterpret_cast<const uint4*>(emean + e2 * DD + lane16 * 8);
        const uint4 u3 = *reinterpret_cast<const uint4*>(emean + e3 * DD + lane16 * 8);
        acc8(a, u0); acc8(b, u1); acc8(a, u2); acc8(b, u3);
    }
    for (; i + 8 < c; i += 16) {
        const int e0 = ilst[i];
        const int e1 = ilst[i + 8];
        const uint4 u0 = *reinterpret_cast<const uint4*>(emean + e0 * DD + lane16 * 8);
        const uint4 u1 = *reinterpret_cast<const uint4*>(emean + e1 * DD + lane16 * 8);
        acc8(a, u0); acc8(b, u1);
    }
    if (i < c) {
        acc8(a, *reinterpret_cast<const uint4*>(emean + ilst[i] * DD + lane16 * 8));
    }
#pragma unroll
    for (int k = 0; k < 8; k++) {
        float v = a[k] + b[k];
        v += __shfl_down(v, 16);
        v += __shfl_down(v, 32);
        a[k] = v;
    }
    if ((tid & 63) < 16) {
#pragma unroll
        for (int k = 0; k < 8; k++) part[wave][lane16][k] = a[k];
    }
    __syncthreads();
    if (tid < 16) {
        const float inv = 1.0f / fmaxf((float)cnt, DEG_EPS);
        const float4 x0a = *reinterpret_cast<const float4*>(x0 + n * DD + tid * 8);
        const float4 x0b = *reinterpret_cast<const float4*>(x0 + n * DD + tid * 8 + 4);
        float y[8];
        y[0] = (part[0][tid][0] + part[1][tid][0]) * inv + x0a.x;
        y[1] = (part[0][tid][1] + part[1][tid][1]) * inv + x0a.y;
        y[2] = (part[0][tid][2] + part[1][tid][2]) * inv + x0a.z;
        y[3] = (part[0][tid][3] + part[1][tid][3]) * inv + x0a.w;
        y[4] = (part[0][tid][4] + part[1][tid][4]) * inv + x0b.x;
        y[5] = (part[0][tid][5] + part[1][tid][5]) * inv + x0b.y;
        y[6] = (part[0][tid][6] + part[1][tid][6]) * inv + x0b.z;
        y[7] = (part[0][tid][7] + part[1][tid][7]) * inv + x0b.w;
        float sm = 0.0f, ss = 0.0f;
#pragma unroll
        for (int k = 0; k < 8; k++) { sm += y[k]; ss += y[k] * y[k]; }
        for (int off = 8; off > 0; off >>= 1) {
            sm += __shfl_down(sm, off);
            ss += __shfl_down(ss, off);
        }
        sm = __shfl(sm, 0);
        ss = __shfl(ss, 0);
        const float mu = sm * (1.0f / 128.0f);
        float var = ss * (1.0f / 128.0f) - mu * mu;
        var = fmaxf(var, 0.0f);
        const float rstd = 1.0f / sqrtf(var + LN_EPS);
        const float4 g0 = *reinterpret_cast<const float4*>(gamma + tid * 8);
        const float4 g1 = *reinterpret_cast<const float4*>(gamma + tid * 8 + 4);
        const float4 b0 = *reinterpret_cast<const float4*>(beta + tid * 8);
        const float4 b1 = *reinterpret_cast<const float4*>(beta + tid * 8 + 4);
        float gg[8] = {g0.x, g0.y, g0.z, g0.w, g1.x, g1.y, g1.z, g1.w};
        float bb[8] = {b0.x, b0.y, b0.z, b0.w, b1.x, b1.y, b1.z, b1.w};
        float o[8];
#pragma unroll
        for (int k = 0; k < 8; k++) o[k] = (y[k] - mu) * rstd * gg[k] + bb[k];
        uint4 u;
        u.x = pack2h(o[0], o[1]); u.y = pack2h(o[2], o[3]);
        u.z = pack2h(o[4], o[5]); u.w = pack2h(o[6], o[7]);
        __half* dst = (tid < 8) ? (xlo + (size_t)n * 64 + tid * 8)
                                : (xhi + (size_t)n * 64 + (tid - 8) * 8);
        *reinterpret_cast<uint4*>(dst) = u;
    }
}

// ---------------------------------------------------------------------------
// Softmax stats (max and sum-exp) over the 5000 logits, one block.
// ---------------------------------------------------------------------------
__global__ __launch_bounds__(1024) void softmax_stats(
    const float* __restrict__ t, float* __restrict__ MS) {
    __shared__ float red[16];
    __shared__ float smax;
    const int tid = threadIdx.x;
    const int wid = tid >> 6;
    float m = -1e30f;
    for (int i = tid; i < EE; i += 1024) m = fmaxf(m, t[i]);
    for (int off = 32; off > 0; off >>= 1) m = fmaxf(m, __shfl_down(m, off));
    if ((tid & 63) == 0) red[wid] = m;
    __syncthreads();
    if (tid < 64) {
        float v = (tid < 16) ? red[tid] : -1e30f;
        for (int off = 8; off > 0; off >>= 1) v = fmaxf(v, __shfl_down(v, off));
        if (tid == 0) smax = v;
    }
    __syncthreads();
    const float M = smax;
    float sum = 0.0f;
    for (int i = tid; i < EE; i += 1024) sum += expf(t[i] - M);
    for (int off = 32; off > 0; off >>= 1) sum += __shfl_down(sum, off);
    if ((tid & 63) == 0) red[wid] = sum;
    __syncthreads();
    if (tid < 64) {
        float v = (tid < 16) ? red[tid] : 0.0f;
        for (int off = 8; off > 0; off >>= 1) v += __shfl_down(v, off);
        if (tid == 0) { MS[0] = M; MS[1] = v; }
    }
}

// ---------------------------------------------------------------------------
// out[d] = sum_e softmax(t)[e] * edge_out[e][d]
// ---------------------------------------------------------------------------
__global__ __launch_bounds__(128) void weighted_sum(
    const float* __restrict__ eout, const float* __restrict__ t,
    const float* __restrict__ MS, float* __restrict__ out) {
    const int d = threadIdx.x;
    const float M = MS[0];
    const float invS = 1.0f / MS[1];
    float acc = 0.0f;
    for (int e = blockIdx.x; e < EE; e += gridDim.x) {
        const float w = expf(t[e] - M);
        acc += w * eout[e * DD + d];
    }
    atomicAdd(&out[d], acc * invS);
}

extern "C" void kernel_launch(void* const* d_in, const int* in_sizes, int n_in,
                              void* d_out, int out_size, void* d_ws, size_t ws_size,
                              hipStream_t stream) {
    const float* x0 = (const float*)d_in[0];     // [N, D]
    const float* H = (const float*)d_in[1];      // [N, E]
    const float* gamma = (const float*)d_in[2];  // [D]
    const float* beta = (const float*)d_in[3];   // [D]
    const float* W = (const float*)d_in[4];      // [D, ATT]
    const float* b = (const float*)d_in[5];      // [ATT]
    const float* qv = (const float*)d_in[6];     // [ATT]
    float* out = (float*)d_out;                  // [D]

    // Workspace layout (all offsets 16B-aligned). Total ~37 MB.
    char* w = (char*)d_ws;
    int* cur = (int*)w;       w += (size_t)EE * CSTRIDE * 4;
    int* nc = (int*)w;        w += (size_t)NN * 4;
    int* el = (int*)w;        w += (size_t)EE * ECAP * 4;
    int* nl = (int*)w;        w += (size_t)NN * NCAP * 4;
    // split fp16 node-feature tables: 6 x N*64*2 B = 6 x 2.56 MB
    __half* xlo0 = (__half*)w; w += (size_t)NN * 64 * 2;
    __half* xhi0 = (__half*)w; w += (size_t)NN * 64 * 2;
    __half* xloA = (__half*)w; w += (size_t)NN * 64 * 2;
    __half* xhiA = (__half*)w; w += (size_t)NN * 64 * 2;
    __half* xloB = (__half*)w; w += (size_t)NN * 64 * 2;
    __half* xhiB = (__half*)w; w += (size_t)NN * 64 * 2;
    __half* emean = (__half*)w; w += (size_t)EE * DD * 2;
    float* eout = (float*)w;  w += (size_t)EE * DD * 4;
    float* t = (float*)w;     w += (size_t)EE * 4;
    float* MS = (float*)w;    w += 16;

    hipMemsetAsync(cur, 0, (size_t)EE * CSTRIDE * 4, stream);
    hipMemsetAsync(d_out, 0, (size_t)DD * sizeof(float), stream);

    build_adj<<<NN, 256, 0, stream>>>(H, cur, nc, el, nl, x0, xlo0, xhi0);

    const __half* inlo = xlo0;
    const __half* inhi = xhi0;
    __half* lob[2] = {xloA, xloB};
    __half* hib[2] = {xhiA, xhiB};
    for (int l = 0; l < NUM_LAYERS; l++) {
        edge_gather_half<<<2 * EE, 256, 0, stream>>>(inlo, inhi, cur, el, emean);
        node_gather_ln16<<<NN, 128, 0, stream>>>(
            emean, nc, nl, x0, gamma, beta, lob[l & 1], hib[l & 1]);
        inlo = lob[l & 1];
        inhi = hib[l & 1];
    }

    edge_final<<<EE, 256, 0, stream>>>(inlo, inhi, cur, el, eout, W, b, qv, t);
    softmax_stats<<<1, 1024, 0, stream>>>(t, MS);
    weighted_sum<<<256, 128, 0, stream>>>(eout, t, MS, out);
}